// Round 5
// baseline (415.384 us; speedup 1.0000x reference)
//
#include <hip/hip_runtime.h>

typedef unsigned short u16;
typedef __bf16 bf16x8 __attribute__((ext_vector_type(8)));
typedef float f32x4 __attribute__((ext_vector_type(4)));

constexpr int B_ = 2, T_ = 2048, D_ = 2048, H_ = 16, HD_ = 128;
constexpr int MROWS = B_ * T_;   // 4096
constexpr int KD = D_;
constexpr int ND = D_;
// softmax in exp2 domain: logits pre-scaled by 1/sqrt(128) * log2(e)
#define SL2E (0.08838834764831845f * 1.4426950408889634f)

__device__ __forceinline__ u16 f2bf(float f) {
  unsigned u = __float_as_uint(f);
  u += 0x7FFF + ((u >> 16) & 1);   // RNE; inputs never NaN
  return (u16)(u >> 16);
}

__device__ __forceinline__ float fexp2(float x) { return __builtin_amdgcn_exp2f(x); }

// async global->LDS, 16B per lane; dest = wave-uniform base + lane*16
__device__ __forceinline__ void async16(const void* g, void* l) {
  __builtin_amdgcn_global_load_lds((__attribute__((address_space(1))) void*)g,
                                   (__attribute__((address_space(3))) void*)l,
                                   16, 0, 0);
}

// single fused f32->bf16 conversion kernel: 6 slabs of 4194304 elems each
__global__ void cvt6_kernel(const float* __restrict__ x,
                            const float* __restrict__ w0, const float* __restrict__ w1,
                            const float* __restrict__ w2, const float* __restrict__ w3,
                            u16* __restrict__ xo,
                            u16* __restrict__ o0, u16* __restrict__ o1,
                            u16* __restrict__ o2, u16* __restrict__ o3) {
  const int y = blockIdx.y;
  const float* in = y == 0 ? x : y == 1 ? x + 4194304 :
                    y == 2 ? w0 : y == 3 ? w1 : y == 4 ? w2 : w3;
  u16* out = y == 0 ? xo : y == 1 ? xo + 4194304 :
             y == 2 ? o0 : y == 3 ? o1 : y == 4 ? o2 : o3;
  const int i = (blockIdx.x * blockDim.x + threadIdx.x) * 4;
  const float4 v = *(const float4*)(in + i);
  ushort4 h;
  h.x = f2bf(v.x); h.y = f2bf(v.y); h.z = f2bf(v.z); h.w = f2bf(v.w);
  *(ushort4*)(out + i) = h;
}

// ---- GEMM core (R0-proven: conflicts == 0, ~806 TF machine rate) ----
template <int MODE>
__device__ __forceinline__ void gemm_body(const u16* __restrict__ A,
                                          const u16* __restrict__ Bw,
                                          const float* __restrict__ bias,
                                          void* __restrict__ outp,
                                          u16* As, u16* Bs) {
  constexpr int BK = 32;
  const int tid = threadIdx.x;
  const int wave = tid >> 6;
  const int lane = tid & 63;
  const int quad = lane >> 4;
  const int l16 = lane & 15;
  const int wm = (wave >> 1) * 64;
  const int wn = (wave & 1) * 64;
  const int mBase = blockIdx.y * 128;
  const int nBase = blockIdx.x * 128;

  f32x4 acc[4][4] = {};

  const int srow = wave * 32 + (lane >> 2);
  const int soff = ((lane & 3) ^ ((lane >> 3) & 3)) * 8;
  const u16* Ag = A + (size_t)(mBase + srow) * KD + soff;
  const u16* Bg = Bw + (size_t)(nBase + srow) * KD + soff;
  u16* AsW0 = &As[(wave * 32) * BK];
  u16* AsW1 = &As[(wave * 32 + 16) * BK];
  u16* BsW0 = &Bs[(wave * 32) * BK];
  u16* BsW1 = &Bs[(wave * 32 + 16) * BK];

  const int sw = (quad ^ ((l16 >> 1) & 3)) * 8;

  for (int k0 = 0; k0 < KD; k0 += BK) {
    __syncthreads();
    async16(Ag + k0, AsW0);
    async16(Ag + 16 * KD + k0, AsW1);
    async16(Bg + k0, BsW0);
    async16(Bg + 16 * KD + k0, BsW1);
    __syncthreads();

    bf16x8 a[4], b[4];
#pragma unroll
    for (int i = 0; i < 4; i++)
      a[i] = *(const bf16x8*)&As[(wm + i * 16 + l16) * BK + sw];
#pragma unroll
    for (int j = 0; j < 4; j++)
      b[j] = *(const bf16x8*)&Bs[(wn + j * 16 + l16) * BK + sw];
#pragma unroll
    for (int i = 0; i < 4; i++)
#pragma unroll
      for (int j = 0; j < 4; j++)
        acc[i][j] = __builtin_amdgcn_mfma_f32_16x16x32_bf16(a[i], b[j], acc[i][j], 0, 0, 0);
  }

  float* outF = (float*)outp;
  u16* outH = (u16*)outp;
#pragma unroll
  for (int i = 0; i < 4; i++) {
#pragma unroll
    for (int j = 0; j < 4; j++) {
      const int col = nBase + wn + j * 16 + l16;
      const float bv = bias[col];
#pragma unroll
      for (int r = 0; r < 4; r++) {
        const int row = mBase + wm + i * 16 + quad * 4 + r;
        const float v = acc[i][j][r] + bv;
        if (MODE == 0) {
          outH[(size_t)row * ND + col] = f2bf(v);
        } else if (MODE == 1) {
          const int bb = row >> 11;
          const int t = row & (T_ - 1);
          const int h = col >> 7;
          const int d = col & (HD_ - 1);
          outH[(size_t)(((bb * H_ + h) << 7) + d) * T_ + t] = f2bf(v);
        } else {
          outF[(size_t)row * ND + col] = v;
        }
      }
    }
  }
}

__global__ __launch_bounds__(256) void gemm_qkv(const u16* __restrict__ A,
                                                const u16* __restrict__ Wq, const u16* __restrict__ Wk,
                                                const u16* __restrict__ Wv,
                                                const float* __restrict__ bq, const float* __restrict__ bk,
                                                const float* __restrict__ bv,
                                                u16* __restrict__ Qo, u16* __restrict__ Ko,
                                                u16* __restrict__ Vo) {
  __shared__ u16 As[128 * 32];
  __shared__ u16 Bs[128 * 32];
  const int z = blockIdx.z;
  const u16* Bw = z == 0 ? Wq : z == 1 ? Wk : Wv;
  const float* bias = z == 0 ? bq : z == 1 ? bk : bv;
  if (z == 2)
    gemm_body<1>(A, Bw, bias, (void*)Vo, As, Bs);
  else
    gemm_body<0>(A, Bw, bias, (void*)(z == 0 ? Qo : Ko), As, Bs);
}

__global__ __launch_bounds__(256) void gemm_out(const u16* __restrict__ A, const u16* __restrict__ Bw,
                                                const float* __restrict__ bias, float* __restrict__ outp) {
  __shared__ u16 As[128 * 32];
  __shared__ u16 Bs[128 * 32];
  gemm_body<2>(A, Bw, bias, (void*)outp, As, Bs);
}

// ---- Flash attention, R5 restructure: one 128-row q-tile per block,
// each wave owns 32 q-rows as TWO 16-row fragment groups (qg=0,1) that
// SHARE every K and V LDS read (kf/vf read once -> 2 MFMA each).
// Per step: 64 MFMA from 44 LDS ops (was 32 MFMA from 38) => -42% LDS/FLOP,
// and K/V HBM traffic halves. Causal balance: work ~ 2p+2, heavy-first
// dispatch (p = 15-bx), 512 blocks at 2/CU self-balance.
// T13 defer-max + deferred lrow reduce retained from R4.
constexpr int PSTR = 72;   // P strip row stride (u16), odd 16B-group count

__global__ __launch_bounds__(256, 2) void attn_kernel(const u16* __restrict__ Q,
                                                      const u16* __restrict__ Kc,
                                                      const u16* __restrict__ Vt,
                                                      u16* __restrict__ O) {
  __shared__ u16 Ks[2][64 * 128];     // [buf][krow][d-chunk swizzled]
  __shared__ u16 Vs[2][128 * 64];     // [buf][d][krow-chunk swizzled]
  __shared__ u16 Ps[4 * 16 * PSTR];   // per-wave P strip (sequential reuse per qg)
  const int tid = threadIdx.x;
  const int wave = tid >> 6;
  const int lane = tid & 63;
  const int quad = lane >> 4;
  const int l16 = lane & 15;
  const int p = 15 - blockIdx.x;      // q-tile index, heaviest first
  const int bh = blockIdx.y;
  const int b = bh >> 4;
  const int h = bh & 15;
  const int nkt = 2 * p + 2;          // causal k-tiles (64 wide) for this q-tile

  // resident Q fragments: qf[qg][kc]; q-row = p*128 + wave*32 + qg*16 + l16
  bf16x8 qf[2][4];
#pragma unroll
  for (int qg = 0; qg < 2; qg++) {
    const u16* Qp = Q + (size_t)(b * T_ + p * 128 + wave * 32 + qg * 16 + l16) * D_ + h * HD_;
#pragma unroll
    for (int kc = 0; kc < 4; kc++)
      qf[qg][kc] = *(const bf16x8*)(Qp + kc * 32 + quad * 8);
  }

  f32x4 o[2][8] = {};
  float mrow[2], lrow[2];
#pragma unroll
  for (int qg = 0; qg < 2; qg++) { mrow[qg] = -__builtin_huge_valf(); lrow[qg] = 0.f; }

  const u16* Kg = Kc + (size_t)(b * T_) * D_ + h * HD_;
  const u16* Vg = Vt + (size_t)((b * H_ + h) * HD_) * T_;
  u16* Pw = &Ps[wave * 16 * PSTR];
  const int swz = (l16 & 7);   // read-side row swizzle

  const u16* kgp[4];
  int klo[4];
  const u16* vgp[4];
  int vlo[4];
#pragma unroll
  for (int c = 0; c < 4; c++) {
    const int krl = wave * 16 + c * 4 + (lane >> 4);
    const int kch = (lane & 15) ^ (krl & 7);
    kgp[c] = Kg + (size_t)krl * D_ + kch * 8;
    klo[c] = (wave * 16 + c * 4) * 128;
    const int vrl = wave * 32 + c * 8 + (lane >> 3);
    const int vch = (lane & 7) ^ (vrl & 7);
    vgp[c] = Vg + (size_t)vrl * T_ + vch * 8;
    vlo[c] = (wave * 32 + c * 8) * 64;
  }

  // prologue: issue kt=0 into buf 0
#pragma unroll
  for (int c = 0; c < 4; c++) async16(kgp[c], &Ks[0][klo[c]]);
#pragma unroll
  for (int c = 0; c < 4; c++) async16(vgp[c], &Vs[0][vlo[c]]);

  for (int kt = 0; kt < nkt; kt++) {
    const int cur = kt & 1;
    __syncthreads();   // implicit vmcnt(0): buf[cur] tiles complete; all waves synced

    if (kt + 1 < nkt) {   // issue next tile into buf[cur^1]; flies behind compute
      const int nxt = cur ^ 1;
#pragma unroll
      for (int c = 0; c < 4; c++) async16(kgp[c] + (size_t)(kt + 1) * 64 * D_, &Ks[nxt][klo[c]]);
#pragma unroll
      for (int c = 0; c < 4; c++) async16(vgp[c] + (size_t)(kt + 1) * 64, &Vs[nxt][vlo[c]]);
    }

    // ---- S^T = K·Q^T for BOTH q-groups, sharing each kf read ----
    f32x4 st[2][4];
#pragma unroll
    for (int nt = 0; nt < 4; nt++) {
      bf16x8 kf[4];
#pragma unroll
      for (int kc = 0; kc < 4; kc++) {
        const int pos = (kc * 4 + quad) ^ swz;
        kf[kc] = *(const bf16x8*)&Ks[cur][(nt * 16 + l16) * 128 + pos * 8];
      }
      f32x4 a0 = {}, a1 = {};
#pragma unroll
      for (int kc = 0; kc < 4; kc++)
        a0 = __builtin_amdgcn_mfma_f32_16x16x32_bf16(kf[kc], qf[0][kc], a0, 0, 0, 0);
#pragma unroll
      for (int kc = 0; kc < 4; kc++)
        a1 = __builtin_amdgcn_mfma_f32_16x16x32_bf16(kf[kc], qf[1][kc], a1, 0, 0, 0);
      st[0][nt] = a0;
      st[1][nt] = a1;
    }

    const bool diag = (kt >= 2 * p);
    bf16x8 pf[2][2];
#pragma unroll
    for (int qg = 0; qg < 2; qg++) {
      // scale + causal mask
#pragma unroll
      for (int nt = 0; nt < 4; nt++)
#pragma unroll
        for (int r = 0; r < 4; r++) {
          float v = st[qg][nt][r] * SL2E;
          if (diag) {
            const int kcol = kt * 64 + nt * 16 + quad * 4 + r;
            const int qrow = p * 128 + wave * 32 + qg * 16 + l16;
            if (kcol > qrow) v = -__builtin_huge_valf();
          }
          st[qg][nt][r] = v;
        }

      // online softmax (all 16 st values of this lane share q = l16)
      float mx = st[qg][0][0];
#pragma unroll
      for (int nt = 0; nt < 4; nt++)
#pragma unroll
        for (int r = 0; r < 4; r++) mx = fmaxf(mx, st[qg][nt][r]);
      mx = fmaxf(mx, __shfl_xor(mx, 16));
      mx = fmaxf(mx, __shfl_xor(mx, 32));

      if (__all(mx - mrow[qg] <= 8.0f)) {
        // T13 defer-max: keep old max; P bounded by 2^8; no O-rescale.
        const float mold = mrow[qg];
        float sum = 0.f;
#pragma unroll
        for (int nt = 0; nt < 4; nt++)
#pragma unroll
          for (int r = 0; r < 4; r++) {
            const float pv = fexp2(st[qg][nt][r] - mold);
            st[qg][nt][r] = pv;
            sum += pv;
          }
        lrow[qg] += sum;           // per-lane partial; reduced in epilogue
      } else {
        const float mnew = fmaxf(mrow[qg], mx);
        const float alpha = fexp2(mrow[qg] - mnew);
        mrow[qg] = mnew;
        float sum = 0.f;
#pragma unroll
        for (int nt = 0; nt < 4; nt++)
#pragma unroll
          for (int r = 0; r < 4; r++) {
            const float pv = fexp2(st[qg][nt][r] - mnew);
            st[qg][nt][r] = pv;
            sum += pv;
          }
        lrow[qg] = lrow[qg] * alpha + sum;

        float af[4];
#pragma unroll
        for (int r = 0; r < 4; r++) af[r] = __shfl(alpha, quad * 4 + r);
#pragma unroll
        for (int dt = 0; dt < 8; dt++)
#pragma unroll
          for (int r = 0; r < 4; r++)
            o[qg][dt][r] *= af[r];
      }

      // P store: [q=l16][k = nt*16 + quad*4 + r] (strip reused qg0 -> qg1;
      // in-wave lgkmcnt ordering suffices, no barrier)
#pragma unroll
      for (int nt = 0; nt < 4; nt++) {
        ushort4 pk;
        pk.x = f2bf(st[qg][nt][0]); pk.y = f2bf(st[qg][nt][1]);
        pk.z = f2bf(st[qg][nt][2]); pk.w = f2bf(st[qg][nt][3]);
        *(ushort4*)&Pw[l16 * PSTR + nt * 16 + quad * 4] = pk;
      }
#pragma unroll
      for (int kc = 0; kc < 2; kc++)
        pf[qg][kc] = *(const bf16x8*)&Pw[l16 * PSTR + kc * 32 + quad * 8];
    }

    // ---- PV for both q-groups, sharing each vf read ----
#pragma unroll
    for (int dt = 0; dt < 8; dt++) {
#pragma unroll
      for (int kc = 0; kc < 2; kc++) {
        const int pos = (kc * 4 + quad) ^ swz;
        bf16x8 vf = *(const bf16x8*)&Vs[cur][(dt * 16 + l16) * 64 + pos * 8];
        o[0][dt] = __builtin_amdgcn_mfma_f32_16x16x32_bf16(pf[0][kc], vf, o[0][dt], 0, 0, 0);
        o[1][dt] = __builtin_amdgcn_mfma_f32_16x16x32_bf16(pf[1][kc], vf, o[1][dt], 0, 0, 0);
      }
    }
  }

#pragma unroll
  for (int qg = 0; qg < 2; qg++) {
    // deferred cross-quad reduce of the per-lane partial sums
    float ltot = lrow[qg];
    ltot += __shfl_xor(ltot, 16);
    ltot += __shfl_xor(ltot, 32);
    float linv[4];
#pragma unroll
    for (int r = 0; r < 4; r++) linv[r] = 1.f / __shfl(ltot, quad * 4 + r);
#pragma unroll
    for (int dt = 0; dt < 8; dt++)
#pragma unroll
      for (int r = 0; r < 4; r++) {
        const int rowg = b * T_ + p * 128 + wave * 32 + qg * 16 + quad * 4 + r;
        const int col = h * HD_ + dt * 16 + l16;
        O[(size_t)rowg * D_ + col] = f2bf(o[qg][dt][r] * linv[r]);
      }
  }
}

extern "C" void kernel_launch(void* const* d_in, const int* in_sizes, int n_in,
                              void* d_out, int out_size, void* d_ws, size_t ws_size,
                              hipStream_t stream) {
  (void)in_sizes; (void)n_in; (void)out_size; (void)ws_size;
  const float* x  = (const float*)d_in[0];
  const float* wq = (const float*)d_in[2];
  const float* bq = (const float*)d_in[3];
  const float* wk = (const float*)d_in[4];
  const float* bk = (const float*)d_in[5];
  const float* wv = (const float*)d_in[6];
  const float* bv = (const float*)d_in[7];
  const float* wo = (const float*)d_in[8];
  const float* bo = (const float*)d_in[9];

  u16* ws  = (u16*)d_ws;
  u16* xb  = ws;                 // 8388608
  u16* wqb = ws + 8388608;
  u16* wkb = ws + 12582912;
  u16* wvb = ws + 16777216;
  u16* wob = ws + 20971520;
  u16* Qb  = ws + 25165824;
  u16* Kb  = ws + 33554432;
  u16* Vtb = ws + 41943040;      // [B,H,HD,T]
  u16* Ob  = ws + 50331648;

  cvt6_kernel<<<dim3(4096, 6), 256, 0, stream>>>(x, wq, wk, wv, wo,
                                                 xb, wqb, wkb, wvb, wob);

  dim3 gg(ND / 128, MROWS / 128, 3);
  gemm_qkv<<<gg, 256, 0, stream>>>(xb, wqb, wkb, wvb, bq, bk, bv, Qb, Kb, Vtb);
  attn_kernel<<<dim3(16, B_ * H_), 256, 0, stream>>>(Qb, Kb, Vtb, Ob);
  gemm_out<<<dim3(ND / 128, MROWS / 128), 256, 0, stream>>>(Ob, wob, bo, (float*)d_out);
}

// Round 6
// 396.468 us; speedup vs baseline: 1.0477x; 1.0477x over previous
//
#include <hip/hip_runtime.h>

typedef unsigned short u16;
typedef __bf16 bf16x8 __attribute__((ext_vector_type(8)));
typedef float f32x4 __attribute__((ext_vector_type(4)));

constexpr int B_ = 2, T_ = 2048, D_ = 2048, H_ = 16, HD_ = 128;
constexpr int MROWS = B_ * T_;   // 4096
constexpr int KD = D_;
constexpr int ND = D_;
// softmax in exp2 domain: logits pre-scaled by 1/sqrt(128) * log2(e)
#define SL2E (0.08838834764831845f * 1.4426950408889634f)

__device__ __forceinline__ u16 f2bf(float f) {
  unsigned u = __float_as_uint(f);
  u += 0x7FFF + ((u >> 16) & 1);   // RNE; inputs never NaN
  return (u16)(u >> 16);
}

__device__ __forceinline__ float fexp2(float x) { return __builtin_amdgcn_exp2f(x); }

// async global->LDS, 16B per lane; dest = wave-uniform base + lane*16
__device__ __forceinline__ void async16(const void* g, void* l) {
  __builtin_amdgcn_global_load_lds((__attribute__((address_space(1))) void*)g,
                                   (__attribute__((address_space(3))) void*)l,
                                   16, 0, 0);
}

// single fused f32->bf16 conversion kernel: 6 slabs of 4194304 elems each
__global__ void cvt6_kernel(const float* __restrict__ x,
                            const float* __restrict__ w0, const float* __restrict__ w1,
                            const float* __restrict__ w2, const float* __restrict__ w3,
                            u16* __restrict__ xo,
                            u16* __restrict__ o0, u16* __restrict__ o1,
                            u16* __restrict__ o2, u16* __restrict__ o3) {
  const int y = blockIdx.y;
  const float* in = y == 0 ? x : y == 1 ? x + 4194304 :
                    y == 2 ? w0 : y == 3 ? w1 : y == 4 ? w2 : w3;
  u16* out = y == 0 ? xo : y == 1 ? xo + 4194304 :
             y == 2 ? o0 : y == 3 ? o1 : y == 4 ? o2 : o3;
  const int i = (blockIdx.x * blockDim.x + threadIdx.x) * 4;
  const float4 v = *(const float4*)(in + i);
  ushort4 h;
  h.x = f2bf(v.x); h.y = f2bf(v.y); h.z = f2bf(v.z); h.w = f2bf(v.w);
  *(ushort4*)(out + i) = h;
}

// ---- GEMM core (R0-proven: conflicts == 0, ~806 TF machine rate) ----
template <int MODE>
__device__ __forceinline__ void gemm_body(const u16* __restrict__ A,
                                          const u16* __restrict__ Bw,
                                          const float* __restrict__ bias,
                                          void* __restrict__ outp,
                                          u16* As, u16* Bs) {
  constexpr int BK = 32;
  const int tid = threadIdx.x;
  const int wave = tid >> 6;
  const int lane = tid & 63;
  const int quad = lane >> 4;
  const int l16 = lane & 15;
  const int wm = (wave >> 1) * 64;
  const int wn = (wave & 1) * 64;
  const int mBase = blockIdx.y * 128;
  const int nBase = blockIdx.x * 128;

  f32x4 acc[4][4] = {};

  const int srow = wave * 32 + (lane >> 2);
  const int soff = ((lane & 3) ^ ((lane >> 3) & 3)) * 8;
  const u16* Ag = A + (size_t)(mBase + srow) * KD + soff;
  const u16* Bg = Bw + (size_t)(nBase + srow) * KD + soff;
  u16* AsW0 = &As[(wave * 32) * BK];
  u16* AsW1 = &As[(wave * 32 + 16) * BK];
  u16* BsW0 = &Bs[(wave * 32) * BK];
  u16* BsW1 = &Bs[(wave * 32 + 16) * BK];

  const int sw = (quad ^ ((l16 >> 1) & 3)) * 8;

  for (int k0 = 0; k0 < KD; k0 += BK) {
    __syncthreads();
    async16(Ag + k0, AsW0);
    async16(Ag + 16 * KD + k0, AsW1);
    async16(Bg + k0, BsW0);
    async16(Bg + 16 * KD + k0, BsW1);
    __syncthreads();

    bf16x8 a[4], b[4];
#pragma unroll
    for (int i = 0; i < 4; i++)
      a[i] = *(const bf16x8*)&As[(wm + i * 16 + l16) * BK + sw];
#pragma unroll
    for (int j = 0; j < 4; j++)
      b[j] = *(const bf16x8*)&Bs[(wn + j * 16 + l16) * BK + sw];
#pragma unroll
    for (int i = 0; i < 4; i++)
#pragma unroll
      for (int j = 0; j < 4; j++)
        acc[i][j] = __builtin_amdgcn_mfma_f32_16x16x32_bf16(a[i], b[j], acc[i][j], 0, 0, 0);
  }

  float* outF = (float*)outp;
  u16* outH = (u16*)outp;
#pragma unroll
  for (int i = 0; i < 4; i++) {
#pragma unroll
    for (int j = 0; j < 4; j++) {
      const int col = nBase + wn + j * 16 + l16;
      const float bv = bias[col];
#pragma unroll
      for (int r = 0; r < 4; r++) {
        const int row = mBase + wm + i * 16 + quad * 4 + r;
        const float v = acc[i][j][r] + bv;
        if (MODE == 0) {
          outH[(size_t)row * ND + col] = f2bf(v);
        } else if (MODE == 1) {
          const int bb = row >> 11;
          const int t = row & (T_ - 1);
          const int h = col >> 7;
          const int d = col & (HD_ - 1);
          outH[(size_t)(((bb * H_ + h) << 7) + d) * T_ + t] = f2bf(v);
        } else {
          outF[(size_t)row * ND + col] = v;
        }
      }
    }
  }
}

__global__ __launch_bounds__(256) void gemm_qkv(const u16* __restrict__ A,
                                                const u16* __restrict__ Wq, const u16* __restrict__ Wk,
                                                const u16* __restrict__ Wv,
                                                const float* __restrict__ bq, const float* __restrict__ bk,
                                                const float* __restrict__ bv,
                                                u16* __restrict__ Qo, u16* __restrict__ Ko,
                                                u16* __restrict__ Vo) {
  __shared__ u16 As[128 * 32];
  __shared__ u16 Bs[128 * 32];
  const int z = blockIdx.z;
  const u16* Bw = z == 0 ? Wq : z == 1 ? Wk : Wv;
  const float* bias = z == 0 ? bq : z == 1 ? bk : bv;
  if (z == 2)
    gemm_body<1>(A, Bw, bias, (void*)Vo, As, Bs);
  else
    gemm_body<0>(A, Bw, bias, (void*)(z == 0 ? Qo : Ko), As, Bs);
}

__global__ __launch_bounds__(256) void gemm_out(const u16* __restrict__ A, const u16* __restrict__ Bw,
                                                const float* __restrict__ bias, float* __restrict__ outp) {
  __shared__ u16 As[128 * 32];
  __shared__ u16 Bs[128 * 32];
  gemm_body<2>(A, Bw, bias, (void*)outp, As, Bs);
}

// ---- Flash attention (R6): R5 structure (128-row q-tile/block, two 16-row
// fragment groups per wave sharing every K/V LDS read) + LOAD-BALANCED
// p-mapping. R5's p = 15-bx gave block b and b+256 the SAME step count
// (2p+2 in 2..32) -> round-robin dispatch co-locates them on one CU ->
// CUs ran 64 or 4 steps against a 34 average (makespan 2x). Fix:
//   p = (bh < 16) ? 15-bx : bx
// bijective over (p,bh); co-located pair does (2bx+2)+(2(15-bx)+2) = 34
// steps uniformly. T13 defer-max + deferred lrow reduce retained.
constexpr int PSTR = 72;   // P strip row stride (u16), odd 16B-group count

__global__ __launch_bounds__(256, 2) void attn_kernel(const u16* __restrict__ Q,
                                                      const u16* __restrict__ Kc,
                                                      const u16* __restrict__ Vt,
                                                      u16* __restrict__ O) {
  __shared__ u16 Ks[2][64 * 128];     // [buf][krow][d-chunk swizzled]
  __shared__ u16 Vs[2][128 * 64];     // [buf][d][krow-chunk swizzled]
  __shared__ u16 Ps[4 * 16 * PSTR];   // per-wave P strip (sequential reuse per qg)
  const int tid = threadIdx.x;
  const int wave = tid >> 6;
  const int lane = tid & 63;
  const int quad = lane >> 4;
  const int l16 = lane & 15;
  const int bh = blockIdx.y;
  const int b = bh >> 4;
  const int h = bh & 15;
  // balanced q-tile mapping (see header comment)
  const int p = (bh < 16) ? (15 - blockIdx.x) : blockIdx.x;
  const int nkt = 2 * p + 2;          // causal k-tiles (64 wide) for this q-tile

  // resident Q fragments: qf[qg][kc]; q-row = p*128 + wave*32 + qg*16 + l16
  bf16x8 qf[2][4];
#pragma unroll
  for (int qg = 0; qg < 2; qg++) {
    const u16* Qp = Q + (size_t)(b * T_ + p * 128 + wave * 32 + qg * 16 + l16) * D_ + h * HD_;
#pragma unroll
    for (int kc = 0; kc < 4; kc++)
      qf[qg][kc] = *(const bf16x8*)(Qp + kc * 32 + quad * 8);
  }

  f32x4 o[2][8] = {};
  float mrow[2], lrow[2];
#pragma unroll
  for (int qg = 0; qg < 2; qg++) { mrow[qg] = -__builtin_huge_valf(); lrow[qg] = 0.f; }

  const u16* Kg = Kc + (size_t)(b * T_) * D_ + h * HD_;
  const u16* Vg = Vt + (size_t)((b * H_ + h) * HD_) * T_;
  u16* Pw = &Ps[wave * 16 * PSTR];
  const int swz = (l16 & 7);   // read-side row swizzle

  const u16* kgp[4];
  int klo[4];
  const u16* vgp[4];
  int vlo[4];
#pragma unroll
  for (int c = 0; c < 4; c++) {
    const int krl = wave * 16 + c * 4 + (lane >> 4);
    const int kch = (lane & 15) ^ (krl & 7);
    kgp[c] = Kg + (size_t)krl * D_ + kch * 8;
    klo[c] = (wave * 16 + c * 4) * 128;
    const int vrl = wave * 32 + c * 8 + (lane >> 3);
    const int vch = (lane & 7) ^ (vrl & 7);
    vgp[c] = Vg + (size_t)vrl * T_ + vch * 8;
    vlo[c] = (wave * 32 + c * 8) * 64;
  }

  // prologue: issue kt=0 into buf 0
#pragma unroll
  for (int c = 0; c < 4; c++) async16(kgp[c], &Ks[0][klo[c]]);
#pragma unroll
  for (int c = 0; c < 4; c++) async16(vgp[c], &Vs[0][vlo[c]]);

  for (int kt = 0; kt < nkt; kt++) {
    const int cur = kt & 1;
    __syncthreads();   // implicit vmcnt(0): buf[cur] tiles complete; all waves synced

    if (kt + 1 < nkt) {   // issue next tile into buf[cur^1]; flies behind compute
      const int nxt = cur ^ 1;
#pragma unroll
      for (int c = 0; c < 4; c++) async16(kgp[c] + (size_t)(kt + 1) * 64 * D_, &Ks[nxt][klo[c]]);
#pragma unroll
      for (int c = 0; c < 4; c++) async16(vgp[c] + (size_t)(kt + 1) * 64, &Vs[nxt][vlo[c]]);
    }

    // ---- S^T = K·Q^T for BOTH q-groups, sharing each kf read ----
    f32x4 st[2][4];
#pragma unroll
    for (int nt = 0; nt < 4; nt++) {
      bf16x8 kf[4];
#pragma unroll
      for (int kc = 0; kc < 4; kc++) {
        const int pos = (kc * 4 + quad) ^ swz;
        kf[kc] = *(const bf16x8*)&Ks[cur][(nt * 16 + l16) * 128 + pos * 8];
      }
      f32x4 a0 = {}, a1 = {};
#pragma unroll
      for (int kc = 0; kc < 4; kc++)
        a0 = __builtin_amdgcn_mfma_f32_16x16x32_bf16(kf[kc], qf[0][kc], a0, 0, 0, 0);
#pragma unroll
      for (int kc = 0; kc < 4; kc++)
        a1 = __builtin_amdgcn_mfma_f32_16x16x32_bf16(kf[kc], qf[1][kc], a1, 0, 0, 0);
      st[0][nt] = a0;
      st[1][nt] = a1;
    }

    const bool diag = (kt >= 2 * p);
    bf16x8 pf[2][2];
#pragma unroll
    for (int qg = 0; qg < 2; qg++) {
      // scale + causal mask
#pragma unroll
      for (int nt = 0; nt < 4; nt++)
#pragma unroll
        for (int r = 0; r < 4; r++) {
          float v = st[qg][nt][r] * SL2E;
          if (diag) {
            const int kcol = kt * 64 + nt * 16 + quad * 4 + r;
            const int qrow = p * 128 + wave * 32 + qg * 16 + l16;
            if (kcol > qrow) v = -__builtin_huge_valf();
          }
          st[qg][nt][r] = v;
        }

      // online softmax (all 16 st values of this lane share q = l16)
      float mx = st[qg][0][0];
#pragma unroll
      for (int nt = 0; nt < 4; nt++)
#pragma unroll
        for (int r = 0; r < 4; r++) mx = fmaxf(mx, st[qg][nt][r]);
      mx = fmaxf(mx, __shfl_xor(mx, 16));
      mx = fmaxf(mx, __shfl_xor(mx, 32));

      if (__all(mx - mrow[qg] <= 8.0f)) {
        // T13 defer-max: keep old max; P bounded by 2^8; no O-rescale.
        const float mold = mrow[qg];
        float sum = 0.f;
#pragma unroll
        for (int nt = 0; nt < 4; nt++)
#pragma unroll
          for (int r = 0; r < 4; r++) {
            const float pv = fexp2(st[qg][nt][r] - mold);
            st[qg][nt][r] = pv;
            sum += pv;
          }
        lrow[qg] += sum;           // per-lane partial; reduced in epilogue
      } else {
        const float mnew = fmaxf(mrow[qg], mx);
        const float alpha = fexp2(mrow[qg] - mnew);
        mrow[qg] = mnew;
        float sum = 0.f;
#pragma unroll
        for (int nt = 0; nt < 4; nt++)
#pragma unroll
          for (int r = 0; r < 4; r++) {
            const float pv = fexp2(st[qg][nt][r] - mnew);
            st[qg][nt][r] = pv;
            sum += pv;
          }
        lrow[qg] = lrow[qg] * alpha + sum;

        float af[4];
#pragma unroll
        for (int r = 0; r < 4; r++) af[r] = __shfl(alpha, quad * 4 + r);
#pragma unroll
        for (int dt = 0; dt < 8; dt++)
#pragma unroll
          for (int r = 0; r < 4; r++)
            o[qg][dt][r] *= af[r];
      }

      // P store: [q=l16][k = nt*16 + quad*4 + r] (strip reused qg0 -> qg1;
      // in-wave lgkmcnt ordering suffices, no barrier)
#pragma unroll
      for (int nt = 0; nt < 4; nt++) {
        ushort4 pk;
        pk.x = f2bf(st[qg][nt][0]); pk.y = f2bf(st[qg][nt][1]);
        pk.z = f2bf(st[qg][nt][2]); pk.w = f2bf(st[qg][nt][3]);
        *(ushort4*)&Pw[l16 * PSTR + nt * 16 + quad * 4] = pk;
      }
#pragma unroll
      for (int kc = 0; kc < 2; kc++)
        pf[qg][kc] = *(const bf16x8*)&Pw[l16 * PSTR + kc * 32 + quad * 8];
    }

    // ---- PV for both q-groups, sharing each vf read ----
#pragma unroll
    for (int dt = 0; dt < 8; dt++) {
#pragma unroll
      for (int kc = 0; kc < 2; kc++) {
        const int pos = (kc * 4 + quad) ^ swz;
        bf16x8 vf = *(const bf16x8*)&Vs[cur][(dt * 16 + l16) * 64 + pos * 8];
        o[0][dt] = __builtin_amdgcn_mfma_f32_16x16x32_bf16(pf[0][kc], vf, o[0][dt], 0, 0, 0);
        o[1][dt] = __builtin_amdgcn_mfma_f32_16x16x32_bf16(pf[1][kc], vf, o[1][dt], 0, 0, 0);
      }
    }
  }

#pragma unroll
  for (int qg = 0; qg < 2; qg++) {
    // deferred cross-quad reduce of the per-lane partial sums
    float ltot = lrow[qg];
    ltot += __shfl_xor(ltot, 16);
    ltot += __shfl_xor(ltot, 32);
    float linv[4];
#pragma unroll
    for (int r = 0; r < 4; r++) linv[r] = 1.f / __shfl(ltot, quad * 4 + r);
#pragma unroll
    for (int dt = 0; dt < 8; dt++)
#pragma unroll
      for (int r = 0; r < 4; r++) {
        const int rowg = b * T_ + p * 128 + wave * 32 + qg * 16 + quad * 4 + r;
        const int col = h * HD_ + dt * 16 + l16;
        O[(size_t)rowg * D_ + col] = f2bf(o[qg][dt][r] * linv[r]);
      }
  }
}

extern "C" void kernel_launch(void* const* d_in, const int* in_sizes, int n_in,
                              void* d_out, int out_size, void* d_ws, size_t ws_size,
                              hipStream_t stream) {
  (void)in_sizes; (void)n_in; (void)out_size; (void)ws_size;
  const float* x  = (const float*)d_in[0];
  const float* wq = (const float*)d_in[2];
  const float* bq = (const float*)d_in[3];
  const float* wk = (const float*)d_in[4];
  const float* bk = (const float*)d_in[5];
  const float* wv = (const float*)d_in[6];
  const float* bv = (const float*)d_in[7];
  const float* wo = (const float*)d_in[8];
  const float* bo = (const float*)d_in[9];

  u16* ws  = (u16*)d_ws;
  u16* xb  = ws;                 // 8388608
  u16* wqb = ws + 8388608;
  u16* wkb = ws + 12582912;
  u16* wvb = ws + 16777216;
  u16* wob = ws + 20971520;
  u16* Qb  = ws + 25165824;
  u16* Kb  = ws + 33554432;
  u16* Vtb = ws + 41943040;      // [B,H,HD,T]
  u16* Ob  = ws + 50331648;

  cvt6_kernel<<<dim3(4096, 6), 256, 0, stream>>>(x, wq, wk, wv, wo,
                                                 xb, wqb, wkb, wvb, wob);

  dim3 gg(ND / 128, MROWS / 128, 3);
  gemm_qkv<<<gg, 256, 0, stream>>>(xb, wqb, wkb, wvb, bq, bk, bv, Qb, Kb, Vtb);
  attn_kernel<<<dim3(16, B_ * H_), 256, 0, stream>>>(Qb, Kb, Vtb, Ob);
  gemm_out<<<dim3(ND / 128, MROWS / 128), 256, 0, stream>>>(Ob, wob, bo, (float*)d_out);
}